// Round 7
// baseline (316.647 us; speedup 1.0000x reference)
//
#include <hip/hip_runtime.h>
#include <hip/hip_bf16.h>
#include <stdint.h>

#define DEV __device__ __forceinline__

typedef __attribute__((ext_vector_type(8))) short short8;
typedef __attribute__((ext_vector_type(8))) _Float16 half8;
typedef __attribute__((ext_vector_type(2))) __fp16 fp16x2;
typedef __attribute__((ext_vector_type(16))) float floatx16;

#if __has_builtin(__builtin_amdgcn_exp2f)
#define EXP2F __builtin_amdgcn_exp2f
#else
#define EXP2F exp2f
#endif

DEV unsigned short f2bf(float f) {
  union { float f; uint32_t u; } v; v.f = f;
  uint32_t u = v.u;
  u += 0x7fffu + ((u >> 16) & 1u);   // RNE
  return (unsigned short)(u >> 16);
}
DEV unsigned short f2h(float f) {
  union { _Float16 h; unsigned short u; } c; c.h = (_Float16)f; return c.u;
}
DEV void async_cp16(const unsigned short* g, unsigned short* l) {
  __builtin_amdgcn_global_load_lds(
      (const __attribute__((address_space(1))) uint32_t*)g,
      (__attribute__((address_space(3))) uint32_t*)l, 16, 0, 0);
}

// ---------------------------------------------------------------------------
// cvt_x: fp32 -> bf16, coalesced.
// ---------------------------------------------------------------------------
__global__ __launch_bounds__(256)
void cvt_x_kernel(const float* __restrict__ x, unsigned short* __restrict__ xb) {
  const size_t i = ((size_t)blockIdx.x * 256 + threadIdx.x) * 4;
  const float4 f = *(const float4*)(x + i);
  ushort4 w;
  w.x = f2bf(f.x); w.y = f2bf(f.y); w.z = f2bf(f.z); w.w = f2bf(f.w);
  *(ushort4*)(xb + i) = w;
}

// ---------------------------------------------------------------------------
// transpose_w: W[K][N] fp32 -> Wt[N][K] bf16. 64x64 LDS tiles.
// ---------------------------------------------------------------------------
__global__ __launch_bounds__(256)
void transpose_w_kernel(const float* __restrict__ W, unsigned short* __restrict__ Wt,
                        int K, int N) {
  __shared__ float tile[64][65];
  const int k0 = blockIdx.y * 64, n0 = blockIdx.x * 64;
  const int tr = threadIdx.x >> 4;
  const int tc = (threadIdx.x & 15) * 4;
#pragma unroll
  for (int it = 0; it < 4; ++it) {
    const int k = tr + it * 16;
    const float4 f = *(const float4*)(W + (size_t)(k0 + k) * N + n0 + tc);
    tile[k][tc + 0] = f.x; tile[k][tc + 1] = f.y;
    tile[k][tc + 2] = f.z; tile[k][tc + 3] = f.w;
  }
  __syncthreads();
#pragma unroll
  for (int it = 0; it < 4; ++it) {
    const int n = tr + it * 16;
    ushort4 w;
    w.x = f2bf(tile[tc + 0][n]); w.y = f2bf(tile[tc + 1][n]);
    w.z = f2bf(tile[tc + 2][n]); w.w = f2bf(tile[tc + 3][n]);
    *(ushort4*)(Wt + (size_t)(n0 + n) * K + k0 + tc) = w;
  }
}

// ---------------------------------------------------------------------------
// bf16 GEMM, 32x32x16 MFMA: C[M,N] = A[M,K]*Bt[N,K]^T + bias[N]
// Block 256 (2x2 waves), tile 256x128 (wave = 128x64, acc 8x16), BK=64.
// global_load_lds width-16, XOR chunk swizzle c^=(row&7); since row stride
// per staging step is 32 (==0 mod 8), swizzled column is step-invariant:
// one base pointer + it*32*K.
// EPI==0: scatter qkv.  EPI==1: fp32 out + bias.
// ---------------------------------------------------------------------------
template <int EPI>
__global__ __launch_bounds__(256)
void gemm_bt_kernel(const unsigned short* __restrict__ A,
                    const unsigned short* __restrict__ Bt,
                    const float* __restrict__ bias, int M, int N, int K,
                    unsigned short* __restrict__ qws,
                    unsigned short* __restrict__ kws,
                    unsigned short* __restrict__ vws,
                    float* __restrict__ out) {
  __shared__ __align__(16) unsigned short As[256 * 64];  // 32 KB
  __shared__ __align__(16) unsigned short Bs[128 * 64];  // 16 KB
  const int tid = threadIdx.x;
  const int wid = tid >> 6;
  const int lane = tid & 63;
  const int l32 = lane & 31, hf = lane >> 5;
  const int wm = wid >> 1, wn = wid & 1;
  const int rowA0 = blockIdx.y * 256;
  const int colB0 = blockIdx.x * 128;

  // Staging bases: thread covers chunk-rows srow + it*32, swizzled col sc.
  const int srow = tid >> 3;                       // 0..31
  const int sc = ((tid & 7) ^ (srow & 7)) * 8;     // element offset
  const unsigned short* gAb = A + (size_t)(rowA0 + srow) * K + sc;
  const unsigned short* gBb = Bt + (size_t)(colB0 + srow) * K + sc;
  unsigned short* lAb = &As[wid * 512];            // + it*2048, wave-uniform
  unsigned short* lBb = &Bs[wid * 512];

  // Fragment read offsets (shorts), un-swizzled.
  int aoff[4][4], boff[2][4];
#pragma unroll
  for (int ti = 0; ti < 4; ++ti)
#pragma unroll
    for (int s = 0; s < 4; ++s) {
      const int ra = wm * 128 + ti * 32 + l32;
      aoff[ti][s] = ra * 64 + ((2 * s + hf) ^ (ra & 7)) * 8;
    }
#pragma unroll
  for (int tj = 0; tj < 2; ++tj)
#pragma unroll
    for (int s = 0; s < 4; ++s) {
      const int rb = wn * 64 + tj * 32 + l32;
      boff[tj][s] = rb * 64 + ((2 * s + hf) ^ (rb & 7)) * 8;
    }

  floatx16 acc[4][2];
#pragma unroll
  for (int i = 0; i < 4; ++i)
#pragma unroll
    for (int j = 0; j < 2; ++j)
#pragma unroll
      for (int r = 0; r < 16; ++r) acc[i][j][r] = 0.f;

  for (int kt = 0; kt < K; kt += 64) {
    __syncthreads();
#pragma unroll
    for (int it = 0; it < 8; ++it)
      async_cp16(gAb + (size_t)it * 32 * K + kt, lAb + it * 2048);
#pragma unroll
    for (int it = 0; it < 4; ++it)
      async_cp16(gBb + (size_t)it * 32 * K + kt, lBb + it * 2048);
    __syncthreads();
#pragma unroll
    for (int s = 0; s < 4; ++s) {
      const short8 b0 = *(const short8*)&Bs[boff[0][s]];
      const short8 b1 = *(const short8*)&Bs[boff[1][s]];
#pragma unroll
      for (int ti = 0; ti < 4; ++ti) {
        const short8 a = *(const short8*)&As[aoff[ti][s]];
        acc[ti][0] = __builtin_amdgcn_mfma_f32_32x32x16_bf16(a, b0, acc[ti][0], 0, 0, 0);
        acc[ti][1] = __builtin_amdgcn_mfma_f32_32x32x16_bf16(a, b1, acc[ti][1], 0, 0, 0);
      }
    }
  }

  // Epilogue. 32x32 C/D: col = l32, row = (reg&3) + 8*(reg>>2) + 4*hf.
  constexpr float QSCALE = 0.18033688011112042f;  // 0.125 * log2(e)
#pragma unroll
  for (int ti = 0; ti < 4; ++ti) {
#pragma unroll
    for (int nj = 0; nj < 2; ++nj) {
      const int col = colB0 + wn * 64 + nj * 32 + l32;
      const float bv = bias[col];
#pragma unroll
      for (int reg = 0; reg < 16; ++reg) {
        const int ri = (reg & 3) + 8 * (reg >> 2) + 4 * hf;
        const int R = rowA0 + wm * 128 + ti * 32 + ri;
        const float v = acc[ti][nj][reg] + bv;
        if constexpr (EPI == 0) {
          const int b = R >> 11, t = R & 2047;
          const int which = col >> 10, c = col & 1023;
          const int h = c >> 6, dd = c & 63;
          const size_t bh = (size_t)(b * 16 + h);
          if (which == 0)
            qws[(bh * 2048 + t) * 64 + dd] = f2bf(v * QSCALE);  // Q, log2 scale
          else if (which == 1)
            kws[(bh * 2048 + t) * 64 + dd] = f2bf(v);           // K [bh][t][d]
          else
            vws[(bh * 64 + dd) * 2048 + t] = f2h(v);            // V^T f16 [bh][d][t]
        } else {
          out[(size_t)R * N + col] = v;
        }
      }
    }
  }
}

// ---------------------------------------------------------------------------
// MFMA flash attention, log2-domain softmax without online max.
// Grid (64 bh, 16 qtiles), block 256 = 4 waves. Stages 256 keys per barrier
// (two 128-key subtiles). S^T = K*Q^T (bf16 32x32x16), O^T = V^T*P^T (f16)
// with register-swap P transpose. K/V staged via global_load_lds + XOR swizzle.
// ---------------------------------------------------------------------------
__global__ __launch_bounds__(256, 2)
void attn_mfma_kernel(const unsigned short* __restrict__ qws,
                      const unsigned short* __restrict__ kws,
                      const unsigned short* __restrict__ vws,
                      unsigned short* __restrict__ yws) {
  constexpr int T = 2048, D = 64;
  __shared__ __align__(16) unsigned short Ks[256 * 64];   // [key][d], 32 KB
  __shared__ __align__(16) unsigned short Vs[2 * 64 * 128];  // 2 halves [d][key]
  const int tid = threadIdx.x;
  const int wid = tid >> 6, lane = tid & 63;
  const int hf = lane >> 5, l32 = lane & 31;
  const int bh = blockIdx.x;
  const int qt = 15 - (int)blockIdx.y;  // heavy tiles first
  const int qbase = qt * 128;
  const unsigned short* Qp = qws + (size_t)bh * T * D;
  const unsigned short* Kp = kws + (size_t)bh * T * D;
  const unsigned short* Vp = vws + (size_t)bh * D * T;

  // K staging: chunk-rows srowK + it*32, swizzled col scK (it-invariant).
  const int srowK = tid >> 3;
  const int scK = ((tid & 7) ^ ((tid >> 3) & 7)) * 8;
  const unsigned short* gKb = Kp + (size_t)srowK * D + scK;   // + (kb+it*32)*D
  unsigned short* lKb = &Ks[wid * 512];                       // + it*2048

  // V staging: half sb = it>>2, d = (it&3)*16 + (tid>>4), swizzled key-chunk.
  const int vd = tid >> 4;                  // 0..15 (d within 16-row group)
  const int vkc = ((tid & 15) ^ vd) * 8;    // swizzled key offset within half
  const unsigned short* gVb = Vp + (size_t)vd * T + vkc;      // + (it&3)*16*T + sb*128 + kb
  unsigned short* lVb = &Vs[wid * 512];                       // + it*2048

  const int q = qbase + wid * 32 + l32;  // this lane's query row
  short8 qf[4];
#pragma unroll
  for (int s = 0; s < 4; ++s)
    qf[s] = *(const short8*)(Qp + (size_t)q * D + s * 16 + hf * 8);

  // Read offsets (shorts), un-swizzled.
  int koff[4], voff[8];
#pragma unroll
  for (int s = 0; s < 4; ++s)
    koff[s] = l32 * 64 + ((2 * s + hf) ^ (l32 & 7)) * 8;    // + sb*8192 + mt*2048
#pragma unroll
  for (int s = 0; s < 8; ++s)
    voff[s] = l32 * 128 + ((2 * s + hf) ^ (l32 & 15)) * 8;  // + sb*8192 + mt2*4096

  floatx16 Oacc[2];
#pragma unroll
  for (int mt2 = 0; mt2 < 2; ++mt2)
#pragma unroll
    for (int i = 0; i < 16; ++i) Oacc[mt2][i] = 0.f;
  float lrun = 0.f;

  const int kmax = (qt + 1) * 128;
  const int nkb = (qt + 2) >> 1;  // number of 256-key stages
  for (int kb2 = 0; kb2 < nkb; ++kb2) {
    const int kb = kb2 * 256;
    __syncthreads();
#pragma unroll
    for (int it = 0; it < 8; ++it)
      async_cp16(gKb + (size_t)(kb + it * 32) * D, lKb + it * 2048);
#pragma unroll
    for (int it = 0; it < 8; ++it)
      async_cp16(gVb + (size_t)(it & 3) * 16 * T + (it >> 2) * 128 + kb,
                 lVb + it * 2048);
    __syncthreads();

#pragma unroll
    for (int sb = 0; sb < 2; ++sb) {
      const int kbs = kb + sb * 128;
      if (kbs >= kmax) break;  // wave-uniform (qt, kb uniform)
      const bool diag = (kbs == qbase);
      const int mtmax = diag ? (wid + 1) : 4;  // wave-uniform

      floatx16 S[4];
#pragma unroll
      for (int mt = 0; mt < 4; ++mt)
        if (mt < mtmax)
#pragma unroll
          for (int i = 0; i < 16; ++i) S[mt][i] = 0.f;

#pragma unroll
      for (int s = 0; s < 4; ++s) {
#pragma unroll
        for (int mt = 0; mt < 4; ++mt)
          if (mt < mtmax) {
            const short8 kf = *(const short8*)&Ks[sb * 8192 + mt * 2048 + koff[s]];
            S[mt] = __builtin_amdgcn_mfma_f32_32x32x16_bf16(kf, qf[s], S[mt], 0, 0, 0);
          }
      }

      if (diag) {  // mask keys > q on the diagonal key-tile
#pragma unroll
        for (int mt = 0; mt < 4; ++mt)
          if (mt == wid) {
#pragma unroll
            for (int r = 0; r < 16; ++r) {
              const int intra = (r & 3) + 8 * (r >> 2) + 4 * hf;
              if (intra > l32) S[mt][r] = -1e30f;
            }
          }
      }

      float tsum = 0.f;
      uint32_t pk[4][8];
#pragma unroll
      for (int mt = 0; mt < 4; ++mt)
        if (mt < mtmax)
#pragma unroll
          for (int t = 0; t < 8; ++t) {
            const float pa = EXP2F(S[mt][2 * t]);      // log2 domain
            const float pb = EXP2F(S[mt][2 * t + 1]);
            tsum += pa + pb;
            union { fp16x2 h; uint32_t u; } cv;
            cv.h = __builtin_amdgcn_cvt_pkrtz(pa, pb);
            pk[mt][t] = cv.u;
          }
      tsum += __shfl_xor(tsum, 32, 64);
      lrun += tsum;

      const int smax = 2 * mtmax;
#pragma unroll
      for (int s = 0; s < 8; ++s)
        if (s < smax) {
          const int mt = s >> 1;
          const int bo = 4 * (s & 1);
          // B-frag regs for k-step s: regs {bo+2h, bo+2h+1} of lanes q, q+32.
          const uint32_t own0 = hf ? pk[mt][bo + 2] : pk[mt][bo];
          const uint32_t own1 = hf ? pk[mt][bo + 3] : pk[mt][bo + 1];
          const uint32_t sendA = hf ? pk[mt][bo] : pk[mt][bo + 2];
          const uint32_t sendB = hf ? pk[mt][bo + 1] : pk[mt][bo + 3];
          const uint32_t recvA = (uint32_t)__shfl_xor((int)sendA, 32, 64);
          const uint32_t recvB = (uint32_t)__shfl_xor((int)sendB, 32, 64);
          union { uint32_t u[4]; half8 h; } bb;
          bb.u[0] = hf ? recvA : own0;
          bb.u[1] = hf ? recvB : own1;
          bb.u[2] = hf ? own0 : recvA;
          bb.u[3] = hf ? own1 : recvB;
#pragma unroll
          for (int mt2 = 0; mt2 < 2; ++mt2) {
            const half8 vf = *(const half8*)&Vs[sb * 8192 + mt2 * 4096 + voff[s]];
            Oacc[mt2] =
                __builtin_amdgcn_mfma_f32_32x32x16_f16(vf, bb.h, Oacc[mt2], 0, 0, 0);
          }
        }
    }
  }

  // Epilogue: O^T C-layout -> y[b][t][h*64+d] bf16.
  const float invl = 1.0f / lrun;
  const int b_ = bh >> 4, h_ = bh & 15;
  unsigned short* yrow = yws + ((size_t)(b_ * 2048 + q)) * 1024 + h_ * 64;
#pragma unroll
  for (int mt2 = 0; mt2 < 2; ++mt2)
#pragma unroll
    for (int t = 0; t < 8; ++t) {
      const int d0 = mt2 * 32 + 2 * (t & 1) + 8 * (t >> 1) + 4 * hf;
      const uint32_t ua = f2bf(Oacc[mt2][2 * t] * invl);
      const uint32_t ub = f2bf(Oacc[mt2][2 * t + 1] * invl);
      *(uint32_t*)&yrow[d0] = ua | (ub << 16);
    }
}

// ---------------------------------------------------------------------------
extern "C" void kernel_launch(void* const* d_in, const int* in_sizes, int n_in,
                              void* d_out, int out_size, void* d_ws, size_t ws_size,
                              hipStream_t stream) {
  (void)in_sizes; (void)n_in; (void)out_size;
  const float* x = (const float*)d_in[0];
  const float* attn_w = (const float*)d_in[1];
  const float* attn_b = (const float*)d_in[2];
  const float* proj_w = (const float*)d_in[3];
  const float* proj_b = (const float*)d_in[4];
  float* out = (float*)d_out;

  const size_t NQ = 8388608;  // 8192*1024
  unsigned short* qws = (unsigned short*)d_ws;
  unsigned short* kws = qws + NQ;
  unsigned short* vws = kws + NQ;
  unsigned short* yws = vws + NQ;
  unsigned short* xb  = yws + NQ;
  unsigned short* wta = xb + NQ;               // 3072*1024
  unsigned short* wtp = wta + 3072 * 1024;     // 1024*1024
  if (ws_size < (5 * NQ + 4 * 1024 * 1024) * sizeof(unsigned short)) return;

  cvt_x_kernel<<<dim3(8192), dim3(256), 0, stream>>>(x, xb);
  transpose_w_kernel<<<dim3(48, 16), dim3(256), 0, stream>>>(attn_w, wta, 1024, 3072);
  transpose_w_kernel<<<dim3(16, 16), dim3(256), 0, stream>>>(proj_w, wtp, 1024, 1024);

  gemm_bt_kernel<0><<<dim3(24, 32), dim3(256), 0, stream>>>(
      xb, wta, attn_b, 8192, 3072, 1024, qws, kws, vws, nullptr);
  attn_mfma_kernel<<<dim3(64, 16), dim3(256), 0, stream>>>(qws, kws, vws, yws);
  gemm_bt_kernel<1><<<dim3(8, 32), dim3(256), 0, stream>>>(
      yws, wtp, proj_b, 8192, 1024, 1024, nullptr, nullptr, nullptr, out);
}

// Round 8
// 283.656 us; speedup vs baseline: 1.1163x; 1.1163x over previous
//
#include <hip/hip_runtime.h>
#include <hip/hip_bf16.h>
#include <stdint.h>

#define DEV __device__ __forceinline__

typedef __attribute__((ext_vector_type(8))) short short8;
typedef __attribute__((ext_vector_type(8))) _Float16 half8;
typedef __attribute__((ext_vector_type(2))) __fp16 fp16x2;
typedef __attribute__((ext_vector_type(16))) float floatx16;

#if __has_builtin(__builtin_amdgcn_exp2f)
#define EXP2F __builtin_amdgcn_exp2f
#else
#define EXP2F exp2f
#endif

DEV unsigned short f2bf(float f) {
  union { float f; uint32_t u; } v; v.f = f;
  uint32_t u = v.u;
  u += 0x7fffu + ((u >> 16) & 1u);   // RNE
  return (unsigned short)(u >> 16);
}
DEV unsigned short f2h(float f) {
  union { _Float16 h; unsigned short u; } c; c.h = (_Float16)f; return c.u;
}
DEV void async_cp16(const unsigned short* g, unsigned short* l) {
  __builtin_amdgcn_global_load_lds(
      (const __attribute__((address_space(1))) uint32_t*)g,
      (__attribute__((address_space(3))) uint32_t*)l, 16, 0, 0);
}

// ---------------------------------------------------------------------------
// cvt_x: fp32 -> bf16, coalesced.
// ---------------------------------------------------------------------------
__global__ __launch_bounds__(256)
void cvt_x_kernel(const float* __restrict__ x, unsigned short* __restrict__ xb) {
  const size_t i = ((size_t)blockIdx.x * 256 + threadIdx.x) * 4;
  const float4 f = *(const float4*)(x + i);
  ushort4 w;
  w.x = f2bf(f.x); w.y = f2bf(f.y); w.z = f2bf(f.z); w.w = f2bf(f.w);
  *(ushort4*)(xb + i) = w;
}

// ---------------------------------------------------------------------------
// transpose_w: W[K][N] fp32 -> Wt[N][K] bf16. 64x64 LDS tiles.
// ---------------------------------------------------------------------------
__global__ __launch_bounds__(256)
void transpose_w_kernel(const float* __restrict__ W, unsigned short* __restrict__ Wt,
                        int K, int N) {
  __shared__ float tile[64][65];
  const int k0 = blockIdx.y * 64, n0 = blockIdx.x * 64;
  const int tr = threadIdx.x >> 4;
  const int tc = (threadIdx.x & 15) * 4;
#pragma unroll
  for (int it = 0; it < 4; ++it) {
    const int k = tr + it * 16;
    const float4 f = *(const float4*)(W + (size_t)(k0 + k) * N + n0 + tc);
    tile[k][tc + 0] = f.x; tile[k][tc + 1] = f.y;
    tile[k][tc + 2] = f.z; tile[k][tc + 3] = f.w;
  }
  __syncthreads();
#pragma unroll
  for (int it = 0; it < 4; ++it) {
    const int n = tr + it * 16;
    ushort4 w;
    w.x = f2bf(tile[tc + 0][n]); w.y = f2bf(tile[tc + 1][n]);
    w.z = f2bf(tile[tc + 2][n]); w.w = f2bf(tile[tc + 3][n]);
    *(ushort4*)(Wt + (size_t)(n0 + n) * K + k0 + tc) = w;
  }
}

// ---------------------------------------------------------------------------
// bf16 GEMM, 32x32x16 MFMA: C[M,N] = A[M,K]*Bt[N,K]^T + bias[N]
// Block 512 thr = 8 waves (4x2), tile 128x128, wave = 32x64 (2 acc tiles =
// 32 AGPRs/wave -> ~100 unified regs -> 2 blocks/CU = 16 waves). BK=64.
// global_load_lds width-16, XOR chunk swizzle c^=(row&7), read un-swizzled.
// EPI==0: scatter qkv.  EPI==1: fp32 out + bias.
// ---------------------------------------------------------------------------
template <int EPI>
__global__ __launch_bounds__(512, 4)
void gemm_bt_kernel(const unsigned short* __restrict__ A,
                    const unsigned short* __restrict__ Bt,
                    const float* __restrict__ bias, int M, int N, int K,
                    unsigned short* __restrict__ qws,
                    unsigned short* __restrict__ kws,
                    unsigned short* __restrict__ vws,
                    float* __restrict__ out) {
  __shared__ __align__(16) unsigned short As[128 * 64];  // 16 KB
  __shared__ __align__(16) unsigned short Bs[128 * 64];  // 16 KB
  const int tid = threadIdx.x;
  const int wid = tid >> 6;             // 0..7
  const int lane = tid & 63;
  const int l32 = lane & 31, hf = lane >> 5;
  const int wm = wid >> 1, wn = wid & 1;  // wave = rows wm*32, cols wn*64
  const int rowA0 = blockIdx.y * 128;
  const int colB0 = blockIdx.x * 128;

  // Staging: 1024 chunks/matrix; CI = it*512 + tid; row = CI>>3 (step 64:
  // swizzle invariant), c = (CI&7)^(row&7). LDS dest lane-contiguous.
  const int srow = tid >> 3;                        // 0..63
  const int sc = ((tid & 7) ^ (srow & 7)) * 8;
  const unsigned short* gAb = A + (size_t)(rowA0 + srow) * K + sc;
  const unsigned short* gBb = Bt + (size_t)(colB0 + srow) * K + sc;
  unsigned short* lAb = &As[wid * 512];             // + it*4096, wave-uniform
  unsigned short* lBb = &Bs[wid * 512];

  // Fragment read offsets (shorts), un-swizzled.
  const int ra = wm * 32 + l32;
  int aoff[4], boff[2][4];
#pragma unroll
  for (int s = 0; s < 4; ++s)
    aoff[s] = ra * 64 + ((2 * s + hf) ^ (ra & 7)) * 8;
#pragma unroll
  for (int tj = 0; tj < 2; ++tj)
#pragma unroll
    for (int s = 0; s < 4; ++s) {
      const int rb = wn * 64 + tj * 32 + l32;
      boff[tj][s] = rb * 64 + ((2 * s + hf) ^ (rb & 7)) * 8;
    }

  floatx16 acc[2];
#pragma unroll
  for (int j = 0; j < 2; ++j)
#pragma unroll
    for (int r = 0; r < 16; ++r) acc[j][r] = 0.f;

  for (int kt = 0; kt < K; kt += 64) {
    __syncthreads();
#pragma unroll
    for (int it = 0; it < 2; ++it) {
      async_cp16(gAb + (size_t)it * 64 * K + kt, lAb + it * 4096);
      async_cp16(gBb + (size_t)it * 64 * K + kt, lBb + it * 4096);
    }
    __syncthreads();
#pragma unroll
    for (int s = 0; s < 4; ++s) {
      const short8 a = *(const short8*)&As[aoff[s]];
      const short8 b0 = *(const short8*)&Bs[boff[0][s]];
      const short8 b1 = *(const short8*)&Bs[boff[1][s]];
      acc[0] = __builtin_amdgcn_mfma_f32_32x32x16_bf16(a, b0, acc[0], 0, 0, 0);
      acc[1] = __builtin_amdgcn_mfma_f32_32x32x16_bf16(a, b1, acc[1], 0, 0, 0);
    }
  }

  // Epilogue. 32x32 C/D: col = l32, row = (reg&3) + 8*(reg>>2) + 4*hf.
  constexpr float QSCALE = 0.18033688011112042f;  // 0.125 * log2(e)
#pragma unroll
  for (int nj = 0; nj < 2; ++nj) {
    const int col = colB0 + wn * 64 + nj * 32 + l32;
    const float bv = bias[col];
#pragma unroll
    for (int reg = 0; reg < 16; ++reg) {
      const int ri = (reg & 3) + 8 * (reg >> 2) + 4 * hf;
      const int R = rowA0 + wm * 32 + ri;
      const float v = acc[nj][reg] + bv;
      if constexpr (EPI == 0) {
        const int b = R >> 11, t = R & 2047;
        const int which = col >> 10, c = col & 1023;
        const int h = c >> 6, dd = c & 63;
        const size_t bh = (size_t)(b * 16 + h);
        if (which == 0)
          qws[(bh * 2048 + t) * 64 + dd] = f2bf(v * QSCALE);  // Q, log2 scale
        else if (which == 1)
          kws[(bh * 2048 + t) * 64 + dd] = f2bf(v);           // K [bh][t][d]
        else
          vws[(bh * 64 + dd) * 2048 + t] = f2h(v);            // V^T f16 [bh][d][t]
      } else {
        out[(size_t)R * N + col] = v;
      }
    }
  }
}

// ---------------------------------------------------------------------------
// MFMA flash attention, log2-domain softmax without online max.
// Grid (64 bh, 16 qtiles), block 256 = 4 waves. Stages 256 keys per barrier
// (two 128-key subtiles). S^T = K*Q^T (bf16 32x32x16), O^T = V^T*P^T (f16)
// with register-swap P transpose. K/V staged via global_load_lds + XOR swizzle.
// ---------------------------------------------------------------------------
__global__ __launch_bounds__(256, 2)
void attn_mfma_kernel(const unsigned short* __restrict__ qws,
                      const unsigned short* __restrict__ kws,
                      const unsigned short* __restrict__ vws,
                      unsigned short* __restrict__ yws) {
  constexpr int T = 2048, D = 64;
  __shared__ __align__(16) unsigned short Ks[256 * 64];      // [key][d], 32 KB
  __shared__ __align__(16) unsigned short Vs[2 * 64 * 128];  // 2 halves [d][key]
  const int tid = threadIdx.x;
  const int wid = tid >> 6, lane = tid & 63;
  const int hf = lane >> 5, l32 = lane & 31;
  const int bh = blockIdx.x;
  const int qt = 15 - (int)blockIdx.y;  // heavy tiles first
  const int qbase = qt * 128;
  const unsigned short* Qp = qws + (size_t)bh * T * D;
  const unsigned short* Kp = kws + (size_t)bh * T * D;
  const unsigned short* Vp = vws + (size_t)bh * D * T;

  // K staging: chunk-rows srowK + it*32, swizzled col scK (it-invariant).
  const int srowK = tid >> 3;
  const int scK = ((tid & 7) ^ ((tid >> 3) & 7)) * 8;
  const unsigned short* gKb = Kp + (size_t)srowK * D + scK;   // + (kb+it*32)*D
  unsigned short* lKb = &Ks[wid * 512];                       // + it*2048

  // V staging: half sb = it>>2, d = (it&3)*16 + (tid>>4), swizzled key-chunk.
  const int vd = tid >> 4;
  const int vkc = ((tid & 15) ^ vd) * 8;
  const unsigned short* gVb = Vp + (size_t)vd * T + vkc;  // + (it&3)*16*T + sb*128 + kb
  unsigned short* lVb = &Vs[wid * 512];                   // + it*2048

  const int q = qbase + wid * 32 + l32;  // this lane's query row
  short8 qf[4];
#pragma unroll
  for (int s = 0; s < 4; ++s)
    qf[s] = *(const short8*)(Qp + (size_t)q * D + s * 16 + hf * 8);

  // Read offsets (shorts), un-swizzled.
  int koff[4], voff[8];
#pragma unroll
  for (int s = 0; s < 4; ++s)
    koff[s] = l32 * 64 + ((2 * s + hf) ^ (l32 & 7)) * 8;    // + sb*8192 + mt*2048
#pragma unroll
  for (int s = 0; s < 8; ++s)
    voff[s] = l32 * 128 + ((2 * s + hf) ^ (l32 & 15)) * 8;  // + sb*8192 + mt2*4096

  floatx16 Oacc[2];
#pragma unroll
  for (int mt2 = 0; mt2 < 2; ++mt2)
#pragma unroll
    for (int i = 0; i < 16; ++i) Oacc[mt2][i] = 0.f;
  float lrun = 0.f;

  const int kmax = (qt + 1) * 128;
  const int nkb = (qt + 2) >> 1;  // number of 256-key stages
  for (int kb2 = 0; kb2 < nkb; ++kb2) {
    const int kb = kb2 * 256;
    __syncthreads();
#pragma unroll
    for (int it = 0; it < 8; ++it)
      async_cp16(gKb + (size_t)(kb + it * 32) * D, lKb + it * 2048);
#pragma unroll
    for (int it = 0; it < 8; ++it)
      async_cp16(gVb + (size_t)(it & 3) * 16 * T + (it >> 2) * 128 + kb,
                 lVb + it * 2048);
    __syncthreads();

#pragma unroll
    for (int sb = 0; sb < 2; ++sb) {
      const int kbs = kb + sb * 128;
      if (kbs >= kmax) break;  // wave-uniform
      const bool diag = (kbs == qbase);
      const int mtmax = diag ? (wid + 1) : 4;  // wave-uniform

      floatx16 S[4];
#pragma unroll
      for (int mt = 0; mt < 4; ++mt)
        if (mt < mtmax)
#pragma unroll
          for (int i = 0; i < 16; ++i) S[mt][i] = 0.f;

#pragma unroll
      for (int s = 0; s < 4; ++s) {
#pragma unroll
        for (int mt = 0; mt < 4; ++mt)
          if (mt < mtmax) {
            const short8 kf = *(const short8*)&Ks[sb * 8192 + mt * 2048 + koff[s]];
            S[mt] = __builtin_amdgcn_mfma_f32_32x32x16_bf16(kf, qf[s], S[mt], 0, 0, 0);
          }
      }

      if (diag) {  // mask keys > q on the diagonal key-tile
#pragma unroll
        for (int mt = 0; mt < 4; ++mt)
          if (mt == wid) {
#pragma unroll
            for (int r = 0; r < 16; ++r) {
              const int intra = (r & 3) + 8 * (r >> 2) + 4 * hf;
              if (intra > l32) S[mt][r] = -1e30f;
            }
          }
      }

      float tsum = 0.f;
      uint32_t pk[4][8];
#pragma unroll
      for (int mt = 0; mt < 4; ++mt)
        if (mt < mtmax)
#pragma unroll
          for (int t = 0; t < 8; ++t) {
            const float pa = EXP2F(S[mt][2 * t]);      // log2 domain
            const float pb = EXP2F(S[mt][2 * t + 1]);
            tsum += pa + pb;
            union { fp16x2 h; uint32_t u; } cv;
            cv.h = __builtin_amdgcn_cvt_pkrtz(pa, pb);
            pk[mt][t] = cv.u;
          }
      tsum += __shfl_xor(tsum, 32, 64);
      lrun += tsum;

      const int smax = 2 * mtmax;
#pragma unroll
      for (int s = 0; s < 8; ++s)
        if (s < smax) {
          const int mt = s >> 1;
          const int bo = 4 * (s & 1);
          const uint32_t own0 = hf ? pk[mt][bo + 2] : pk[mt][bo];
          const uint32_t own1 = hf ? pk[mt][bo + 3] : pk[mt][bo + 1];
          const uint32_t sendA = hf ? pk[mt][bo] : pk[mt][bo + 2];
          const uint32_t sendB = hf ? pk[mt][bo + 1] : pk[mt][bo + 3];
          const uint32_t recvA = (uint32_t)__shfl_xor((int)sendA, 32, 64);
          const uint32_t recvB = (uint32_t)__shfl_xor((int)sendB, 32, 64);
          union { uint32_t u[4]; half8 h; } bb;
          bb.u[0] = hf ? recvA : own0;
          bb.u[1] = hf ? recvB : own1;
          bb.u[2] = hf ? own0 : recvA;
          bb.u[3] = hf ? own1 : recvB;
#pragma unroll
          for (int mt2 = 0; mt2 < 2; ++mt2) {
            const half8 vf = *(const half8*)&Vs[sb * 8192 + mt2 * 4096 + voff[s]];
            Oacc[mt2] =
                __builtin_amdgcn_mfma_f32_32x32x16_f16(vf, bb.h, Oacc[mt2], 0, 0, 0);
          }
        }
    }
  }

  // Epilogue: O^T C-layout -> y[b][t][h*64+d] bf16.
  const float invl = 1.0f / lrun;
  const int b_ = bh >> 4, h_ = bh & 15;
  unsigned short* yrow = yws + ((size_t)(b_ * 2048 + q)) * 1024 + h_ * 64;
#pragma unroll
  for (int mt2 = 0; mt2 < 2; ++mt2)
#pragma unroll
    for (int t = 0; t < 8; ++t) {
      const int d0 = mt2 * 32 + 2 * (t & 1) + 8 * (t >> 1) + 4 * hf;
      const uint32_t ua = f2bf(Oacc[mt2][2 * t] * invl);
      const uint32_t ub = f2bf(Oacc[mt2][2 * t + 1] * invl);
      *(uint32_t*)&yrow[d0] = ua | (ub << 16);
    }
}

// ---------------------------------------------------------------------------
extern "C" void kernel_launch(void* const* d_in, const int* in_sizes, int n_in,
                              void* d_out, int out_size, void* d_ws, size_t ws_size,
                              hipStream_t stream) {
  (void)in_sizes; (void)n_in; (void)out_size;
  const float* x = (const float*)d_in[0];
  const float* attn_w = (const float*)d_in[1];
  const float* attn_b = (const float*)d_in[2];
  const float* proj_w = (const float*)d_in[3];
  const float* proj_b = (const float*)d_in[4];
  float* out = (float*)d_out;

  const size_t NQ = 8388608;  // 8192*1024
  unsigned short* qws = (unsigned short*)d_ws;
  unsigned short* kws = qws + NQ;
  unsigned short* vws = kws + NQ;
  unsigned short* yws = vws + NQ;
  unsigned short* xb  = yws + NQ;
  unsigned short* wta = xb + NQ;               // 3072*1024
  unsigned short* wtp = wta + 3072 * 1024;     // 1024*1024
  if (ws_size < (5 * NQ + 4 * 1024 * 1024) * sizeof(unsigned short)) return;

  cvt_x_kernel<<<dim3(8192), dim3(256), 0, stream>>>(x, xb);
  transpose_w_kernel<<<dim3(48, 16), dim3(256), 0, stream>>>(attn_w, wta, 1024, 3072);
  transpose_w_kernel<<<dim3(16, 16), dim3(256), 0, stream>>>(proj_w, wtp, 1024, 1024);

  gemm_bt_kernel<0><<<dim3(24, 64), dim3(512), 0, stream>>>(
      xb, wta, attn_b, 8192, 3072, 1024, qws, kws, vws, nullptr);
  attn_mfma_kernel<<<dim3(64, 16), dim3(256), 0, stream>>>(qws, kws, vws, yws);
  gemm_bt_kernel<1><<<dim3(8, 64), dim3(512), 0, stream>>>(
      yws, wtp, proj_b, 8192, 1024, 1024, nullptr, nullptr, nullptr, out);
}